// Round 5
// baseline (1082.317 us; speedup 1.0000x reference)
//
#include <hip/hip_runtime.h>
#include <cstdint>
#include <cstddef>

// Problem constants (from reference)
constexpr int HID  = 3072;   // hidden size (K of GEMM1, N of GEMM2)
constexpr int ITR  = 8192;   // intermediate size
constexpr int MTOK = 8192;   // B*S = 4*2048 tokens

typedef int i32x4 __attribute__((ext_vector_type(4)));

// ---------- helpers ----------

// RNE fp32 -> bf16 bits
__device__ inline unsigned short f2bf(float f) {
  unsigned int u = __float_as_uint(f);
  u = (u + 0x7FFFu + ((u >> 16) & 1u)) >> 16;
  return (unsigned short)u;
}

// async global->LDS, 16B per lane. LDS dest is wave-uniform base; HW writes
// dest + lane*16.
__device__ inline void gl2lds16(const void* g, void* l) {
  __builtin_amdgcn_global_load_lds(
      (const __attribute__((address_space(1))) unsigned int*)(uintptr_t)g,
      (__attribute__((address_space(3))) unsigned int*)(unsigned int)(uintptr_t)l,
      16, 0, 0);
}

// ---------- prep kernels (unchanged) ----------

__global__ __launch_bounds__(256) void quant_x(
    const float* __restrict__ x, signed char* __restrict__ xq,
    float* __restrict__ qs) {
  const int row = blockIdx.x;
  const int t = threadIdx.x;
  const int wave = t >> 6, lane = t & 63;
  const float4* xr = (const float4*)(x + (size_t)row * HID);  // 768 float4
  float4 v[3];
  float m = 0.f;
#pragma unroll
  for (int k = 0; k < 3; k++) {
    v[k] = xr[t + 256 * k];
    m = fmaxf(m, fmaxf(fmaxf(fabsf(v[k].x), fabsf(v[k].y)),
                       fmaxf(fabsf(v[k].z), fabsf(v[k].w))));
  }
#pragma unroll
  for (int off = 32; off >= 1; off >>= 1) m = fmaxf(m, __shfl_down(m, off));
  __shared__ float wm[4];
  if (lane == 0) wm[wave] = m;
  __syncthreads();
  const float am = fmaxf(fmaxf(wm[0], wm[1]), fmaxf(wm[2], wm[3]));
  const float inv = (am > 1e-30f) ? 127.f / am : 0.f;
  if (t == 0) qs[row] = (am > 1e-30f) ? am / 127.f : 1.f;
  int* out = (int*)(xq + (size_t)row * HID);
#pragma unroll
  for (int k = 0; k < 3; k++) {
    int r0 = __float2int_rn(v[k].x * inv);
    int r1 = __float2int_rn(v[k].y * inv);
    int r2 = __float2int_rn(v[k].z * inv);
    int r3 = __float2int_rn(v[k].w * inv);
    out[t + 256 * k] =
        (r0 & 255) | ((r1 & 255) << 8) | ((r2 & 255) << 16) | ((r3 & 255) << 24);
  }
}

// w1 int32 -> int8 with gate/up 16-row interleave
__global__ __launch_bounds__(256) void cvt_w1_i8(
    const int* __restrict__ in, signed char* __restrict__ out) {
  const int nw = 2 * ITR * (HID / 4);
  int i = blockIdx.x * 256 + threadIdx.x;
  if (i >= nw) return;
  const int R  = i / (HID / 4);
  const int c4 = i % (HID / 4);
  const int q = R >> 5, rm = R & 31;
  const int orig = (rm < 16) ? (q * 16 + rm) : (ITR + q * 16 + (rm - 16));
  int4 w = ((const int4*)(in + (size_t)orig * HID))[c4];
  ((int*)out)[(size_t)R * (HID / 4) + c4] =
      (w.x & 255) | ((w.y & 255) << 8) | ((w.z & 255) << 16) | ((w.w & 255) << 24);
}

// w2 int32 -> int8, layout preserved ([HID, ITR], k contiguous)
__global__ __launch_bounds__(256) void cvt_w2_i8(
    const int* __restrict__ in, signed char* __restrict__ out) {
  const int nw = HID * (ITR / 4);
  int i = blockIdx.x * 256 + threadIdx.x;
  if (i >= nw) return;
  int4 w = ((const int4*)in)[i];
  ((int*)out)[i] =
      (w.x & 255) | ((w.y & 255) << 8) | ((w.z & 255) << 16) | ((w.w & 255) << 24);
}

// per-token int8 quantization of hidden (bf16 in)
__global__ __launch_bounds__(256) void quant_h(
    const unsigned short* __restrict__ h, signed char* __restrict__ hq,
    float* __restrict__ qh) {
  const int row = blockIdx.x;
  const int t = threadIdx.x;
  const int wave = t >> 6, lane = t & 63;
  const uint4* hr = (const uint4*)(h + (size_t)row * ITR);  // 1024 uint4
  uint4 v[4];
  float f[32];
  float m = 0.f;
#pragma unroll
  for (int k = 0; k < 4; k++) {
    v[k] = hr[t + 256 * k];
    const unsigned int w[4] = {v[k].x, v[k].y, v[k].z, v[k].w};
#pragma unroll
    for (int j = 0; j < 4; j++) {
      float lo = __uint_as_float(w[j] << 16);
      float hi = __uint_as_float(w[j] & 0xFFFF0000u);
      f[k * 8 + 2 * j]     = lo;
      f[k * 8 + 2 * j + 1] = hi;
      m = fmaxf(m, fmaxf(fabsf(lo), fabsf(hi)));
    }
  }
#pragma unroll
  for (int off = 32; off >= 1; off >>= 1) m = fmaxf(m, __shfl_down(m, off));
  __shared__ float wm[4];
  if (lane == 0) wm[wave] = m;
  __syncthreads();
  const float am = fmaxf(fmaxf(wm[0], wm[1]), fmaxf(wm[2], wm[3]));
  const float inv = (am > 1e-30f) ? 127.f / am : 0.f;
  if (t == 0) qh[row] = (am > 1e-30f) ? am / 127.f : 1.f;
  int* out = (int*)(hq + (size_t)row * ITR);
#pragma unroll
  for (int k = 0; k < 4; k++) {
#pragma unroll
    for (int j = 0; j < 2; j++) {
      int r0 = __float2int_rn(f[k * 8 + 4 * j]     * inv);
      int r1 = __float2int_rn(f[k * 8 + 4 * j + 1] * inv);
      int r2 = __float2int_rn(f[k * 8 + 4 * j + 2] * inv);
      int r3 = __float2int_rn(f[k * 8 + 4 * j + 3] * inv);
      out[(t + 256 * k) * 2 + j] =
          (r0 & 255) | ((r1 & 255) << 8) | ((r2 & 255) << 16) | ((r3 & 255) << 24);
    }
  }
}

// ---------- GEMM v6: chunked MFMA + counted-lgkm fragment pipeline ----------
// Per K-tile: 4 chunks of 8 MFMA. Frag reads for chunk c+1 stay IN FLIGHT
// during chunk c's MFMAs (counted lgkmcnt(2), never 0 mid-tile); next tile's
// {bv0-3, av0, av1} prefetched during chunk 3 (counted lgkmcnt(6)).
// 4-buffer LDS (128 KB), per-iter vmcnt(4) completes stage(t+2) with t+3 in
// flight -> prefetched frag reads target a buffer guaranteed staged+barriered.
// asm "memory" clobbers delimit read groups (group-level counts are sound
// under intra-group reordering); sched_barrier(0) after every counted wait
// pins MFMAs (rule: hipcc hoists reg-only MFMA past asm waits otherwise).

__global__ __launch_bounds__(512, 2) void gemm1_i8_v6(
    const signed char* __restrict__ A, const signed char* __restrict__ B,
    const float* __restrict__ qs, const float* __restrict__ scales,
    unsigned short* __restrict__ Hout) {
  constexpr int K = HID, NT = K / 64;     // 48 K-tiles
  constexpr int MB = MTOK / 256;          // 32
  constexpr int NB = (2 * ITR) / 256;     // 64
  constexpr int PN = 4;

  const int tid = threadIdx.x;
  const int wave = tid >> 6, lane = tid & 63;

  // XCD-bijective swizzle (2048 % 8 == 0) + PN-panel, mb-major inside panel
  const int bid = blockIdx.x;
  const int wg = (bid & 7) * (MB * NB / 8) + (bid >> 3);
  const int panel = wg / (PN * MB);
  const int rem = wg - panel * (PN * MB);
  const int nb = panel * PN + (rem & (PN - 1));
  const int mb = rem / PN;
  const int m0 = mb * 256;
  const int n0 = nb * 256;  // interleaved gate/up column space [0, 2*ITR)

  __shared__ __align__(16) signed char sA[4][256 * 64];  // 64 KB
  __shared__ __align__(16) signed char sB[4][256 * 64];  // 64 KB

  const int srow  = wave * 32 + (lane >> 2);
  const int chunk = (lane & 3) ^ ((lane >> 3) & 3);  // XOR-swizzled src chunk
  const signed char* Ag = A + (size_t)(m0 + srow) * K + chunk * 16;
  const signed char* Bg = B + (size_t)(n0 + srow) * K + chunk * 16;
  const int ldsw = (wave * 32) * 64;  // wave-uniform LDS staging base (bytes)

  auto stageA2 = [&](int ks, int b) {
    gl2lds16(Ag + ks * 64,          &sA[b][ldsw]);
    gl2lds16(Ag + ks * 64 + 16 * K, &sA[b][ldsw + 1024]);
  };
  auto stageB2 = [&](int ks, int b) {
    gl2lds16(Bg + ks * 64,          &sB[b][ldsw]);
    gl2lds16(Bg + ks * 64 + 16 * K, &sB[b][ldsw + 1024]);
  };

  i32x4 acc[8][4];
#pragma unroll
  for (int i = 0; i < 8; i++)
#pragma unroll
    for (int j = 0; j < 4; j++) acc[i][j] = (i32x4){0, 0, 0, 0};

  const int wr = wave >> 2, wc = wave & 3;
  const int ml = lane & 15;
  const int q  = lane >> 4;
  const int slot = (q ^ ((ml >> 1) & 3)) * 16;  // swizzled read slot (bytes)
  const int aoff = (wr * 128 + ml) * 64 + slot; // av row base (bytes)
  const int boff = (wc * 64 + ml) * 64 + slot;  // bv row base (bytes)

  // prologue: 3 tiles staged; vmcnt(4) completes t0,t1 (t2 in flight)
  stageA2(0, 0); stageB2(0, 0);
  stageA2(1, 1); stageB2(1, 1);
  stageA2(2, 2); stageB2(2, 2);
  asm volatile("s_waitcnt vmcnt(4)" ::: "memory");
  __builtin_amdgcn_s_barrier();

  // prefetch P(0): bv0-3, av0, av1 from buffer 0 (6 lgkm in flight)
  i32x4 bv[4], a0, a1;
  {
    const signed char* b_ = sB[0];
    const signed char* a_ = sA[0];
#pragma unroll
    for (int j = 0; j < 4; j++) bv[j] = *(const i32x4*)&b_[boff + j * 1024];
    a0 = *(const i32x4*)&a_[aoff];
    a1 = *(const i32x4*)&a_[aoff + 1024];
  }

  for (int t = 0; t < NT; ++t) {
    const signed char* a_ = sA[t & 3];
    i32x4 nbv[4], na0, na1;
    // ---- G1: stage A-half(t+3); issue av2,av3; wait P(t) ----
    if (t + 3 < NT) stageA2(t + 3, (t + 3) & 3);
    i32x4 a2 = *(const i32x4*)&a_[aoff + 2 * 1024];
    i32x4 a3 = *(const i32x4*)&a_[aoff + 3 * 1024];
    asm volatile("s_waitcnt lgkmcnt(2)" ::: "memory");
    __builtin_amdgcn_sched_barrier(0);
    __builtin_amdgcn_s_setprio(1);
#pragma unroll
    for (int j = 0; j < 4; j++) {
      acc[0][j] = __builtin_amdgcn_mfma_i32_16x16x64_i8(a0, bv[j], acc[0][j], 0, 0, 0);
      acc[1][j] = __builtin_amdgcn_mfma_i32_16x16x64_i8(a1, bv[j], acc[1][j], 0, 0, 0);
    }
    __builtin_amdgcn_s_setprio(0);
    // ---- G2: stage B-half(t+3); issue av4,av5; wait av2,av3 ----
    if (t + 3 < NT) stageB2(t + 3, (t + 3) & 3);
    i32x4 a4 = *(const i32x4*)&a_[aoff + 4 * 1024];
    i32x4 a5 = *(const i32x4*)&a_[aoff + 5 * 1024];
    asm volatile("s_waitcnt lgkmcnt(2)" ::: "memory");
    __builtin_amdgcn_sched_barrier(0);
    __builtin_amdgcn_s_setprio(1);
#pragma unroll
    for (int j = 0; j < 4; j++) {
      acc[2][j] = __builtin_amdgcn_mfma_i32_16x16x64_i8(a2, bv[j], acc[2][j], 0, 0, 0);
      acc[3][j] = __builtin_amdgcn_mfma_i32_16x16x64_i8(a3, bv[j], acc[3][j], 0, 0, 0);
    }
    __builtin_amdgcn_s_setprio(0);
    // ---- G3: issue av6,av7; wait av4,av5 ----
    i32x4 a6 = *(const i32x4*)&a_[aoff + 6 * 1024];
    i32x4 a7 = *(const i32x4*)&a_[aoff + 7 * 1024];
    asm volatile("s_waitcnt lgkmcnt(2)" ::: "memory");
    __builtin_amdgcn_sched_barrier(0);
    __builtin_amdgcn_s_setprio(1);
#pragma unroll
    for (int j = 0; j < 4; j++) {
      acc[4][j] = __builtin_amdgcn_mfma_i32_16x16x64_i8(a4, bv[j], acc[4][j], 0, 0, 0);
      acc[5][j] = __builtin_amdgcn_mfma_i32_16x16x64_i8(a5, bv[j], acc[5][j], 0, 0, 0);
    }
    __builtin_amdgcn_s_setprio(0);
    // ---- G4: prefetch P(t+1); wait av6,av7 (P' stays in flight) ----
    if (t + 1 < NT) {
      const signed char* bn = sB[(t + 1) & 3];
      const signed char* an = sA[(t + 1) & 3];
#pragma unroll
      for (int j = 0; j < 4; j++) nbv[j] = *(const i32x4*)&bn[boff + j * 1024];
      na0 = *(const i32x4*)&an[aoff];
      na1 = *(const i32x4*)&an[aoff + 1024];
      asm volatile("s_waitcnt lgkmcnt(6)" ::: "memory");
    } else {
      asm volatile("s_waitcnt lgkmcnt(0)" ::: "memory");
    }
    __builtin_amdgcn_sched_barrier(0);
    __builtin_amdgcn_s_setprio(1);
#pragma unroll
    for (int j = 0; j < 4; j++) {
      acc[6][j] = __builtin_amdgcn_mfma_i32_16x16x64_i8(a6, bv[j], acc[6][j], 0, 0, 0);
      acc[7][j] = __builtin_amdgcn_mfma_i32_16x16x64_i8(a7, bv[j], acc[7][j], 0, 0, 0);
    }
    __builtin_amdgcn_s_setprio(0);
    // ---- rotate stages/buffers ----
    if (t + 3 < NT) asm volatile("s_waitcnt vmcnt(4)" ::: "memory");
    else            asm volatile("s_waitcnt vmcnt(0)" ::: "memory");
    __builtin_amdgcn_s_barrier();
#pragma unroll
    for (int j = 0; j < 4; j++) bv[j] = nbv[j];
    a0 = na0; a1 = na1;
  }

  // Epilogue: j pairs (0,1),(2,3) = (gate,up) for the same 16 hidden cols.
  // C/D layout: col = lane&15, row = (lane>>4)*4 + reg
#pragma unroll
  for (int jp = 0; jp < 2; jp++) {
    const int hcol = (n0 + wc * 64) / 2 + jp * 16 + ml;
    const float sg = scales[hcol];
    const float su = scales[ITR + hcol];
#pragma unroll
    for (int i = 0; i < 8; i++) {
      const int mrow = m0 + wr * 128 + i * 16 + q * 4;
#pragma unroll
      for (int r = 0; r < 4; r++) {
        const float rowqs = qs[mrow + r];
        float g = (float)acc[i][2 * jp][r] * sg * rowqs;
        float u = (float)acc[i][2 * jp + 1][r] * su * rowqs;
        float h = (g / (1.f + __expf(-g))) * u;  // silu(g)*u
        Hout[(size_t)(mrow + r) * ITR + hcol] = f2bf(h);
      }
    }
  }
}

// gemm2: 256x128 tile (768 blocks = 3 exact rounds), same counted-lgkm
// pipeline with 2 chunks of 8 MFMA; 4-buffer LDS (96 KB), per-iter vmcnt(3).
__global__ __launch_bounds__(512, 2) void gemm2_i8_v6(
    const signed char* __restrict__ A, const signed char* __restrict__ B,
    const float* __restrict__ qh, const float* __restrict__ scales,
    float* __restrict__ Cout) {
  constexpr int K = ITR, N = HID, NT = K / 64;  // 128 K-tiles
  constexpr int MB = MTOK / 256;                // 32
  constexpr int NB = N / 128;                   // 24
  constexpr int PN = 2;

  const int tid = threadIdx.x;
  const int wave = tid >> 6, lane = tid & 63;

  const int bid = blockIdx.x;  // 768 blocks, 768 % 8 == 0
  const int wg = (bid & 7) * (MB * NB / 8) + (bid >> 3);
  const int panel = wg / (PN * MB);
  const int rem = wg - panel * (PN * MB);
  const int nb = panel * PN + (rem & (PN - 1));
  const int mb = rem / PN;
  const int m0 = mb * 256;
  const int n0 = nb * 128;

  __shared__ __align__(16) signed char sA[4][256 * 64];  // 64 KB
  __shared__ __align__(16) signed char sB[4][128 * 64];  // 32 KB

  const int srowA = wave * 32 + (lane >> 2);
  const int srowB = wave * 16 + (lane >> 2);
  const int chunk = (lane & 3) ^ ((lane >> 3) & 3);
  const signed char* Ag = A + (size_t)(m0 + srowA) * K + chunk * 16;
  const signed char* Bg = B + (size_t)(n0 + srowB) * K + chunk * 16;
  const int ldswA = (wave * 32) * 64;
  const int ldswB = (wave * 16) * 64;

  auto stageA2 = [&](int ks, int b) {
    gl2lds16(Ag + ks * 64,          &sA[b][ldswA]);
    gl2lds16(Ag + ks * 64 + 16 * K, &sA[b][ldswA + 1024]);
  };
  auto stageB1 = [&](int ks, int b) {
    gl2lds16(Bg + ks * 64, &sB[b][ldswB]);
  };

  i32x4 acc[4][4];
#pragma unroll
  for (int i = 0; i < 4; i++)
#pragma unroll
    for (int j = 0; j < 4; j++) acc[i][j] = (i32x4){0, 0, 0, 0};

  const int wr = wave >> 1, wc = wave & 1;  // 4M x 2N, per-wave 64x64
  const int ml = lane & 15;
  const int q  = lane >> 4;
  const int slot = (q ^ ((ml >> 1) & 3)) * 16;
  const int aoff = (wr * 64 + ml) * 64 + slot;
  const int boff = (wc * 64 + ml) * 64 + slot;

  stageA2(0, 0); stageB1(0, 0);
  stageA2(1, 1); stageB1(1, 1);
  stageA2(2, 2); stageB1(2, 2);
  asm volatile("s_waitcnt vmcnt(3)" ::: "memory");
  __builtin_amdgcn_s_barrier();

  // prefetch P(0): av0-3, bv0, bv1 (6 lgkm in flight)
  i32x4 av[4], b0, b1;
  {
    const signed char* a_ = sA[0];
    const signed char* b_ = sB[0];
#pragma unroll
    for (int i = 0; i < 4; i++) av[i] = *(const i32x4*)&a_[aoff + i * 1024];
    b0 = *(const i32x4*)&b_[boff];
    b1 = *(const i32x4*)&b_[boff + 1024];
  }

  for (int t = 0; t < NT; ++t) {
    const signed char* b_ = sB[t & 3];
    i32x4 nav[4], nb0, nb1;
    // ---- G1: stage A(t+3); issue bv2,bv3; wait P(t) ----
    if (t + 3 < NT) stageA2(t + 3, (t + 3) & 3);
    i32x4 b2 = *(const i32x4*)&b_[boff + 2 * 1024];
    i32x4 b3 = *(const i32x4*)&b_[boff + 3 * 1024];
    asm volatile("s_waitcnt lgkmcnt(2)" ::: "memory");
    __builtin_amdgcn_sched_barrier(0);
    __builtin_amdgcn_s_setprio(1);
#pragma unroll
    for (int i = 0; i < 4; i++) {
      acc[i][0] = __builtin_amdgcn_mfma_i32_16x16x64_i8(av[i], b0, acc[i][0], 0, 0, 0);
      acc[i][1] = __builtin_amdgcn_mfma_i32_16x16x64_i8(av[i], b1, acc[i][1], 0, 0, 0);
    }
    __builtin_amdgcn_s_setprio(0);
    // ---- G2: stage B(t+3); prefetch P(t+1); wait bv2,bv3 ----
    if (t + 3 < NT) stageB1(t + 3, (t + 3) & 3);
    if (t + 1 < NT) {
      const signed char* an = sA[(t + 1) & 3];
      const signed char* bn = sB[(t + 1) & 3];
#pragma unroll
      for (int i = 0; i < 4; i++) nav[i] = *(const i32x4*)&an[aoff + i * 1024];
      nb0 = *(const i32x4*)&bn[boff];
      nb1 = *(const i32x4*)&bn[boff + 1024];
      asm volatile("s_waitcnt lgkmcnt(6)" ::: "memory");
    } else {
      asm volatile("s_waitcnt lgkmcnt(0)" ::: "memory");
    }
    __builtin_amdgcn_sched_barrier(0);
    __builtin_amdgcn_s_setprio(1);
#pragma unroll
    for (int i = 0; i < 4; i++) {
      acc[i][2] = __builtin_amdgcn_mfma_i32_16x16x64_i8(av[i], b2, acc[i][2], 0, 0, 0);
      acc[i][3] = __builtin_amdgcn_mfma_i32_16x16x64_i8(av[i], b3, acc[i][3], 0, 0, 0);
    }
    __builtin_amdgcn_s_setprio(0);
    if (t + 3 < NT) asm volatile("s_waitcnt vmcnt(3)" ::: "memory");
    else            asm volatile("s_waitcnt vmcnt(0)" ::: "memory");
    __builtin_amdgcn_s_barrier();
#pragma unroll
    for (int i = 0; i < 4; i++) av[i] = nav[i];
    b0 = nb0; b1 = nb1;
  }

#pragma unroll
  for (int j = 0; j < 4; j++) {
    const int n = n0 + wc * 64 + j * 16 + ml;
    const float sn = scales[n];
#pragma unroll
    for (int i = 0; i < 4; i++) {
      const int mrow = m0 + wr * 64 + i * 16 + q * 4;
#pragma unroll
      for (int r = 0; r < 4; r++) {
        Cout[(size_t)(mrow + r) * N + n] = (float)acc[i][j][r] * sn * qh[mrow + r];
      }
    }
  }
}

// ---------- launch ----------

extern "C" void kernel_launch(void* const* d_in, const int* in_sizes, int n_in,
                              void* d_out, int out_size, void* d_ws, size_t ws_size,
                              hipStream_t stream) {
  const float* x  = (const float*)d_in[0];  // [4,2048,3072] fp32
  const int*   w1 = (const int*)d_in[1];    // [16384,3072] int32 (int8-valued)
  const float* s1 = (const float*)d_in[2];  // [16384]
  const int*   w2 = (const int*)d_in[3];    // [3072,8192] int32
  const float* s2 = (const float*)d_in[4];  // [3072]
  float* out = (float*)d_out;               // [4,2048,3072] fp32

  signed char* xq  = (signed char*)d_ws;
  float* qs        = (float*)(xq + (size_t)MTOK * HID);
  signed char* w1q = (signed char*)(qs + MTOK);
  signed char* w2q = w1q + (size_t)2 * ITR * HID;
  unsigned short* hid = (unsigned short*)(w2q + (size_t)HID * ITR);
  signed char* hq  = (signed char*)(hid + (size_t)MTOK * ITR);
  float* qh        = (float*)(hq + (size_t)MTOK * ITR);

  quant_x<<<MTOK, 256, 0, stream>>>(x, xq, qs);
  {
    int nw = 2 * ITR * (HID / 4);
    cvt_w1_i8<<<(nw + 255) / 256, 256, 0, stream>>>(w1, w1q);
  }
  {
    int nw = HID * (ITR / 4);
    cvt_w2_i8<<<(nw + 255) / 256, 256, 0, stream>>>(w2, w2q);
  }

  // GEMM1 (int8, 256^2, chunked counted-lgkm pipeline): hid[8192,8192] bf16
  {
    unsigned nblocks = (2 * ITR / 256) * (MTOK / 256);  // 64*32 = 2048
    gemm1_i8_v6<<<nblocks, 512, 0, stream>>>(xq, w1q, qs, s1, hid);
  }
  quant_h<<<MTOK, 256, 0, stream>>>(hid, hq, qh);
  // GEMM2 (int8, 256x128, chunked counted-lgkm pipeline): out[8192,3072] fp32
  {
    unsigned nblocks = (HID / 128) * (MTOK / 256);  // 24*32 = 768
    gemm2_i8_v6<<<nblocks, 512, 0, stream>>>(hq, w2q, qh, s2, out);
  }
}